// Round 1
// baseline (146.604 us; speedup 1.0000x reference)
//
#include <hip/hip_runtime.h>
#include <cmath>

// Problem constants (from reference): B=32768, N=17, D=2, K=3, H=64
#define NBATCH 32768
#define NJOINT 17
#define OUT0_ELEMS (NBATCH * NJOINT * 15)          // 8,355,840  out[B,N,3,5]
#define KJS_OFF    OUT0_ELEMS                      // 8,355,840  k_js[B,N]
#define MASK_OFF   (KJS_OFF + NBATCH * NJOINT)     // 8,912,896  mask[B,N,3]

__device__ __forceinline__ float sel3f(int i, float a, float b, float c) {
    return (i == 0) ? a : ((i == 1) ? b : c);
}

// One thread per (b, n) point. n = blockIdx.y so every weight read is
// wave-uniform -> scalar loads (s_load), weights never touch LDS/VGPR bandwidth.
// k/w logits in fp64 to make the discrete argmax / argsort decisions match a
// high-precision reference; bulk bMLP in fp32 fma (2% absmax tolerance).
__global__ __launch_bounds__(256) void mdn_fused(
    const float* __restrict__ pred_pts,
    const float* __restrict__ kW1, const float* __restrict__ kb1,
    const float* __restrict__ kW2, const float* __restrict__ kb2,
    const float* __restrict__ wW1, const float* __restrict__ wb1,
    const float* __restrict__ wW2, const float* __restrict__ wb2,
    const float* __restrict__ bW1, const float* __restrict__ bb1,
    const float* __restrict__ bW2, const float* __restrict__ bb2,
    float* __restrict__ out)
{
    const int n = blockIdx.y;
    const int b = blockIdx.x * 256 + threadIdx.x;
    const int p = b * NJOINT + n;

    const float2 xv = *reinterpret_cast<const float2*>(pred_pts + 2 * p);
    const float x0f = xv.x, x1f = xv.y;
    const double x0 = (double)x0f, x1 = (double)x1f;

    // ---------------- kMLP (fp64) : 2 -> 64 -> 3, argmax+1 -----------------
    double kl0, kl1, kl2;
    {
        const float* W1a = kW1 + n * 128;      // kW1[n][0][h]
        const float* W1b = W1a + 64;           // kW1[n][1][h]
        const float* b1  = kb1 + n * 64;
        const float* W2  = kW2 + n * 192;      // kW2[n][h][j], j<3
        kl0 = (double)kb2[n * 3 + 0];
        kl1 = (double)kb2[n * 3 + 1];
        kl2 = (double)kb2[n * 3 + 2];
        #pragma unroll 8
        for (int h = 0; h < 64; ++h) {
            double hv = fma(x1, (double)W1b[h], fma(x0, (double)W1a[h], (double)b1[h]));
            hv = fmax(hv, 0.0);
            kl0 = fma(hv, (double)W2[h * 3 + 0], kl0);
            kl1 = fma(hv, (double)W2[h * 3 + 1], kl1);
            kl2 = fma(hv, (double)W2[h * 3 + 2], kl2);
        }
    }
    int kj = 0;  // first-occurrence argmax (jnp.argmax semantics)
    {
        double m = kl0;
        if (kl1 > m) { m = kl1; kj = 1; }
        if (kl2 > m) { kj = 2; }
    }

    // ---------------- wMLP (fp64) : 2 -> 64 -> 3, softmax + argsort --------
    double wl0, wl1, wl2;
    {
        const float* W1a = wW1 + n * 128;
        const float* W1b = W1a + 64;
        const float* b1  = wb1 + n * 64;
        const float* W2  = wW2 + n * 192;
        wl0 = (double)wb2[n * 3 + 0];
        wl1 = (double)wb2[n * 3 + 1];
        wl2 = (double)wb2[n * 3 + 2];
        #pragma unroll 8
        for (int h = 0; h < 64; ++h) {
            double hv = fma(x1, (double)W1b[h], fma(x0, (double)W1a[h], (double)b1[h]));
            hv = fmax(hv, 0.0);
            wl0 = fma(hv, (double)W2[h * 3 + 0], wl0);
            wl1 = fma(hv, (double)W2[h * 3 + 1], wl1);
            wl2 = fma(hv, (double)W2[h * 3 + 2], wl2);
        }
    }
    // stable descending argsort of 3 (jnp.argsort(-w): ties -> lower index first)
    int i0 = 0;
    {
        double m = wl0;
        if (wl1 > m) { m = wl1; i0 = 1; }
        if (wl2 > m) { i0 = 2; }
    }
    const int ia = (i0 == 0) ? 1 : 0;           // remaining indices, ia < ib
    const int ib = (i0 == 2) ? 1 : 2;
    const double wa = ia ? wl1 : wl0;
    const double wb = (ib == 1) ? wl1 : wl2;
    const int i1 = (wb > wa) ? ib : ia;
    const int i2 = (wb > wa) ? ia : ib;

    // softmax weights (original, unsorted order goes into out[...,0])
    const double mw = fmax(fmax(wl0, wl1), wl2);
    const float e0 = __expf((float)(wl0 - mw));
    const float e1 = __expf((float)(wl1 - mw));
    const float e2 = __expf((float)(wl2 - mw));
    const float inv = 1.0f / (e0 + e1 + e2);
    const float p0 = e0 * inv, p1 = e1 * inv, p2 = e2 * inv;

    // ---------------- bMLP (fp32) : 2 -> 128 -> 12 -------------------------
    float acc[12];
    {
        const float* W1a = bW1 + n * 256;      // bW1[n][0][h]
        const float* W1b = W1a + 128;          // bW1[n][1][h]
        const float* b1  = bb1 + n * 128;
        const float* W2  = bW2 + n * 1536;     // bW2[n][h][j], j<12
        const float* b2  = bb2 + n * 12;
        #pragma unroll
        for (int j = 0; j < 12; ++j) acc[j] = b2[j];
        #pragma unroll 4
        for (int h = 0; h < 128; ++h) {
            float hv = fmaxf(fmaf(x1f, W1b[h], fmaf(x0f, W1a[h], b1[h])), 0.0f);
            #pragma unroll
            for (int j = 0; j < 12; ++j)
                acc[j] = fmaf(hv, W2[h * 12 + j], acc[j]);
        }
    }
    // per component c: acc[c*4+0..1] = mu, exp(acc[c*4+2..3]) = sigma

    // ---------------- epilogue: gather by sort order, write ----------------
    float r[15];
    r[0]  = p0; r[5] = p1; r[10] = p2;

    r[1]  = sel3f(i0, acc[0], acc[4], acc[8]);
    r[2]  = sel3f(i0, acc[1], acc[5], acc[9]);
    r[3]  = __expf(sel3f(i0, acc[2], acc[6], acc[10]));
    r[4]  = __expf(sel3f(i0, acc[3], acc[7], acc[11]));

    r[6]  = sel3f(i1, acc[0], acc[4], acc[8]);
    r[7]  = sel3f(i1, acc[1], acc[5], acc[9]);
    r[8]  = __expf(sel3f(i1, acc[2], acc[6], acc[10]));
    r[9]  = __expf(sel3f(i1, acc[3], acc[7], acc[11]));

    r[11] = sel3f(i2, acc[0], acc[4], acc[8]);
    r[12] = sel3f(i2, acc[1], acc[5], acc[9]);
    r[13] = __expf(sel3f(i2, acc[2], acc[6], acc[10]));
    r[14] = __expf(sel3f(i2, acc[3], acc[7], acc[11]));

    float* o = out + (size_t)p * 15;
    #pragma unroll
    for (int i = 0; i < 15; ++i) o[i] = r[i];

    out[KJS_OFF + p] = (float)(kj + 1);

    float* mk = out + MASK_OFF + (size_t)p * 3;
    mk[0] = 1.0f;
    mk[1] = (kj >= 1) ? 1.0f : 0.0f;
    mk[2] = (kj >= 2) ? 1.0f : 0.0f;
}

extern "C" void kernel_launch(void* const* d_in, const int* in_sizes, int n_in,
                              void* d_out, int out_size, void* d_ws, size_t ws_size,
                              hipStream_t stream) {
    (void)in_sizes; (void)n_in; (void)d_ws; (void)ws_size; (void)out_size;
    dim3 grid(NBATCH / 256, NJOINT);
    mdn_fused<<<grid, 256, 0, stream>>>(
        (const float*)d_in[0],
        (const float*)d_in[1], (const float*)d_in[2],
        (const float*)d_in[3], (const float*)d_in[4],
        (const float*)d_in[5], (const float*)d_in[6],
        (const float*)d_in[7], (const float*)d_in[8],
        (const float*)d_in[9], (const float*)d_in[10],
        (const float*)d_in[11], (const float*)d_in[12],
        (float*)d_out);
}